// Round 1
// baseline (1283.872 us; speedup 1.0000x reference)
//
#include <hip/hip_runtime.h>

#define TOK 98
#define QSCALE 0.17677669529663687f  // 1/sqrt(32)

// LDS layout (floats), total 13288 floats = 53,152 B  -> 3 blocks/CU
#define SXC 0                  // [98][16]  x c-tile, stride 16
#define SWC 1568               // [96][20]  w c-tile, stride 20
#define SQ  (1568 + 1920)      // [98][36]  Q (padded stride: lane-distinct reads)
#define SK  (SQ + 98 * 36)     // [98][32]  K (broadcast reads, no pad needed)
#define SV  (SK + 98 * 32)     // [98][32]  V
#define SMEM_TOT (SV + 98 * 32)

// Kernel 1: fused qkv-slice GEMM + attention per (window b, head h).
// grid = B*4, block = 256.
__global__ __launch_bounds__(256, 2) void attn_fused(
    const float* __restrict__ x,       // [B][98][128]
    const float* __restrict__ mask,    // [L][98][98]
    const float* __restrict__ qkv_w,   // [384][128]
    const float* __restrict__ qkv_b,   // [384]
    const float* __restrict__ rel,     // [4][507]
    float* __restrict__ out,           // [B][98][128]
    int Lmask)
{
    __shared__ float smem[SMEM_TOT];

    const int tid = threadIdx.x;
    const int b = blockIdx.x >> 2;
    const int h = blockIdx.x & 3;

    // ---------------- Stage 1: qkv slice GEMM (98 tokens x 96 rows) ----------
    // thread tile: 7 tokens (n = nt*7+i, clamped) x 6 rows (r = rt + 16*j)
    const int rt = tid & 15;
    const int nt = tid >> 4;

    float acc[7][6];
#pragma unroll
    for (int i = 0; i < 7; i++)
#pragma unroll
        for (int j = 0; j < 6; j++) acc[i][j] = 0.f;

    const float* xb = x + (long)b * (TOK * 128);

    for (int ct = 0; ct < 8; ct++) {           // 8 c-tiles of 16
        __syncthreads();
        for (int e = tid; e < TOK * 16; e += 256) {
            int n = e >> 4, c = e & 15;
            smem[SXC + n * 16 + c] = xb[n * 128 + ct * 16 + c];
        }
        for (int e = tid; e < 96 * 16; e += 256) {
            int r = e >> 4, c = e & 15;
            int rf = (r >> 5) * 128 + h * 32 + (r & 31);
            smem[SWC + r * 20 + c] = qkv_w[rf * 128 + ct * 16 + c];
        }
        __syncthreads();
#pragma unroll
        for (int cc = 0; cc < 16; cc += 4) {
            float4 xf[7];
#pragma unroll
            for (int i = 0; i < 7; i++) {
                int n = nt * 7 + i; n = n > 97 ? 97 : n;   // clamp; dup rows discarded
                xf[i] = *(const float4*)&smem[SXC + n * 16 + cc];
            }
            float4 wf[6];
#pragma unroll
            for (int j = 0; j < 6; j++)
                wf[j] = *(const float4*)&smem[SWC + (rt + 16 * j) * 20 + cc];
#pragma unroll
            for (int i = 0; i < 7; i++)
#pragma unroll
                for (int j = 0; j < 6; j++) {
                    acc[i][j] = fmaf(xf[i].x, wf[j].x, acc[i][j]);
                    acc[i][j] = fmaf(xf[i].y, wf[j].y, acc[i][j]);
                    acc[i][j] = fmaf(xf[i].z, wf[j].z, acc[i][j]);
                    acc[i][j] = fmaf(xf[i].w, wf[j].w, acc[i][j]);
                }
        }
    }

    // write Q (bias+scale), K, V to LDS.  s = j>>1 is compile-time per unrolled j.
#pragma unroll
    for (int j = 0; j < 6; j++) {
        const int s = j >> 1;
        const int d = rt + 16 * (j & 1);
        const float bv = qkv_b[s * 128 + h * 32 + d];
#pragma unroll
        for (int i = 0; i < 7; i++) {
            int n = nt * 7 + i;
            if (n < TOK) {
                float v = acc[i][j] + bv;
                if (s == 0) {
                    v *= QSCALE;
                    smem[SQ + n * 36 + d] = v;
                } else {
                    smem[SK + (s - 1) * (TOK * 32) + n * 32 + d] = v;
                }
            }
        }
    }
    __syncthreads();

    // ---------------- Stage 2-4: attention. 2 threads per row. ----------------
    if (tid < 2 * TOK) {
        const int i = tid >> 1;       // row 0..97
        const int half = tid & 1;     // j-half: j = half*49 + jj

        float q[32];
#pragma unroll
        for (int c = 0; c < 32; c += 4) {
            float4 t = *(const float4*)&smem[SQ + i * 36 + c];
            q[c] = t.x; q[c + 1] = t.y; q[c + 2] = t.z; q[c + 3] = t.w;
        }

        const int ti = i / 49;
        const int hi = (i % 49) / 7;
        const int wi = i % 7;
        const float* relrow = rel + h * 507;
        const float* maskrow = mask + (long)(b % Lmask) * (TOK * TOK) + i * TOK + half * 49;

        float S[49];
#pragma unroll
        for (int jj = 0; jj < 49; jj++) {
            const float* kr = &smem[SK + (half * 49 + jj) * 32];
            float d0 = 0.f, d1 = 0.f, d2 = 0.f, d3 = 0.f;
#pragma unroll
            for (int c = 0; c < 32; c += 4) {
                float4 kv = *(const float4*)&kr[c];
                d0 = fmaf(q[c], kv.x, d0);
                d1 = fmaf(q[c + 1], kv.y, d1);
                d2 = fmaf(q[c + 2], kv.z, d2);
                d3 = fmaf(q[c + 3], kv.w, d3);
            }
            const int hj = jj / 7, wj = jj - 7 * hj;   // tj == half
            const int ridx = (ti - half + 1) * 169 + (hi - hj + 6) * 13 + (wi - wj + 6);
            S[jj] = (d0 + d1) + (d2 + d3) + relrow[ridx] + maskrow[jj];
        }

        // softmax across the full row (pair-reduce with partner lane)
        float m = S[0];
#pragma unroll
        for (int jj = 1; jj < 49; jj++) m = fmaxf(m, S[jj]);
        m = fmaxf(m, __shfl_xor(m, 1));
        float sum = 0.f;
#pragma unroll
        for (int jj = 0; jj < 49; jj++) { float e = __expf(S[jj] - m); S[jj] = e; sum += e; }
        sum += __shfl_xor(sum, 1);
        const float inv = 1.0f / sum;

        float O[32];
#pragma unroll
        for (int c = 0; c < 32; c++) O[c] = 0.f;
#pragma unroll
        for (int jj = 0; jj < 49; jj++) {
            const float p = S[jj];
            const float* vr = &smem[SV + (half * 49 + jj) * 32];
#pragma unroll
            for (int c = 0; c < 32; c += 4) {
                float4 vv = *(const float4*)&vr[c];
                O[c]     = fmaf(p, vv.x, O[c]);
                O[c + 1] = fmaf(p, vv.y, O[c + 1]);
                O[c + 2] = fmaf(p, vv.z, O[c + 2]);
                O[c + 3] = fmaf(p, vv.w, O[c + 3]);
            }
        }
#pragma unroll
        for (int c = 0; c < 32; c++) O[c] = (O[c] + __shfl_xor(O[c], 1)) * inv;

        float* orow = out + ((long)b * TOK + i) * 128 + h * 32 + half * 16;
#pragma unroll
        for (int c = 0; c < 16; c += 4) {
            float4 st = make_float4(O[half * 16 + c], O[half * 16 + c + 1],
                                    O[half * 16 + c + 2], O[half * 16 + c + 3]);
            *(float4*)&orow[c] = st;
        }
    }
}

// Kernel 2: proj GEMM in-place on d_out. Each block owns 64 rows: loads them to
// LDS (so in-place overwrite is safe), multiplies by proj_w^T, adds proj_b.
__global__ __launch_bounds__(256, 2) void proj_inplace(
    const float* __restrict__ proj_w,  // [128][128]
    const float* __restrict__ proj_b,  // [128]
    float* __restrict__ out,
    int totalRows)
{
    __shared__ float sIn[64 * 132];    // stride 132 (16B-aligned, conflict-free)
    __shared__ float sW[128 * 36];     // c-chunk of proj_w, stride 36

    const int tid = threadIdx.x;
    const int rowBase = blockIdx.x * 64;

    for (int e = tid; e < 64 * 128; e += 256) {
        int n = e >> 7, c = e & 127;
        int row = rowBase + n;
        sIn[n * 132 + c] = (row < totalRows) ? out[(long)row * 128 + c] : 0.f;
    }

    const int ct2 = tid & 15;   // -> co = ct2 + 16*j (coalesced stores)
    const int nt2 = tid >> 4;   // -> n  = nt2*4 + i

    float acc[4][8];
#pragma unroll
    for (int i = 0; i < 4; i++)
#pragma unroll
        for (int j = 0; j < 8; j++) acc[i][j] = 0.f;

    for (int ch = 0; ch < 4; ch++) {   // 4 c-chunks of 32
        __syncthreads();               // sIn ready (ch=0) / prev chunk compute done
        for (int e = tid; e < 128 * 32; e += 256) {
            int r = e >> 5, c = e & 31;
            sW[r * 36 + c] = proj_w[r * 128 + ch * 32 + c];
        }
        __syncthreads();
#pragma unroll
        for (int c = 0; c < 32; c += 4) {
            float4 xf[4];
#pragma unroll
            for (int i = 0; i < 4; i++)
                xf[i] = *(const float4*)&sIn[(nt2 * 4 + i) * 132 + ch * 32 + c];
            float4 wf[8];
#pragma unroll
            for (int j = 0; j < 8; j++)
                wf[j] = *(const float4*)&sW[(ct2 + 16 * j) * 36 + c];
#pragma unroll
            for (int i = 0; i < 4; i++)
#pragma unroll
                for (int j = 0; j < 8; j++) {
                    acc[i][j] = fmaf(xf[i].x, wf[j].x, acc[i][j]);
                    acc[i][j] = fmaf(xf[i].y, wf[j].y, acc[i][j]);
                    acc[i][j] = fmaf(xf[i].z, wf[j].z, acc[i][j]);
                    acc[i][j] = fmaf(xf[i].w, wf[j].w, acc[i][j]);
                }
        }
    }

#pragma unroll
    for (int j = 0; j < 8; j++) {
        const int co = ct2 + 16 * j;
        const float bv = proj_b[co];
#pragma unroll
        for (int i = 0; i < 4; i++) {
            int row = rowBase + nt2 * 4 + i;
            if (row < totalRows)
                out[(long)row * 128 + co] = acc[i][j] + bv;
        }
    }
}

extern "C" void kernel_launch(void* const* d_in, const int* in_sizes, int n_in,
                              void* d_out, int out_size, void* d_ws, size_t ws_size,
                              hipStream_t stream) {
    const float* x      = (const float*)d_in[0];
    const float* mask   = (const float*)d_in[1];
    const float* qkv_w  = (const float*)d_in[2];
    const float* qkv_b  = (const float*)d_in[3];
    const float* rel    = (const float*)d_in[4];
    const float* proj_w = (const float*)d_in[5];
    const float* proj_b = (const float*)d_in[6];
    float* out = (float*)d_out;

    const int B     = in_sizes[0] / (TOK * 128);
    const int Lmask = in_sizes[1] / (TOK * TOK);

    attn_fused<<<B * 4, 256, 0, stream>>>(x, mask, qkv_w, qkv_b, rel, out, Lmask);

    const int totalRows = B * TOK;
    const int grid2 = (totalRows + 63) / 64;
    proj_inplace<<<grid2, 256, 0, stream>>>(proj_w, proj_b, out, totalRows);
}

// Round 3
// 688.699 us; speedup vs baseline: 1.8642x; 1.8642x over previous
//
#include <hip/hip_runtime.h>

typedef __attribute__((ext_vector_type(8))) _Float16 half8;
typedef __attribute__((ext_vector_type(16))) float f32x16;

#define TOK 98
#define QSCALE 0.17677669529663687f  // 1/sqrt(32)

// LDS layout in _Float16 units.
//  Qs: [128][40]  at 0        (rows m, cols d<32, +pad -> 80B stride, 16B aligned)
//  Ks: [128][40]  at 5120
//  Ps: [128][120] at 0        (overlaps Qs+Ks; written only after QK reads done)
//  Vs: [128][40]  at 15360
#define QS 0
#define KS (128 * 40)
#define PS 0
#define VS 15360
#define LDSH (15360 + 128 * 40)   // 20480 halves = 40960 B (+ rel floats below)

__device__ inline half8 cvt8(float4 a, float4 b) {
    half8 r;
    r[0] = (_Float16)a.x; r[1] = (_Float16)a.y; r[2] = (_Float16)a.z; r[3] = (_Float16)a.w;
    r[4] = (_Float16)b.x; r[5] = (_Float16)b.y; r[6] = (_Float16)b.z; r[7] = (_Float16)b.w;
    return r;
}

__global__ __launch_bounds__(256, 3) void attn_mfma(
    const float* __restrict__ x,       // [B][98][128]
    const float* __restrict__ mask,    // [L][98][98]
    const float* __restrict__ qkv_w,   // [384][128]
    const float* __restrict__ qkv_b,   // [384]
    const float* __restrict__ rel,     // [4][507]
    float* __restrict__ out,           // [B][98][128] (pre-proj)
    int Lmask)
{
    __shared__ __align__(16) _Float16 lh[LDSH];
    __shared__ float rel_lds[507];

    const int tid  = threadIdx.x;
    const int b    = blockIdx.x >> 2;
    const int h    = blockIdx.x & 3;
    const int wv   = tid >> 6;        // wave 0..3: owns token rows [32wv, 32wv+32)
    const int lane = tid & 63;
    const int t32  = lane & 31;
    const int half = lane >> 5;

    // stage rel row for this head; zero V pad rows 98..111 (PV k-padding)
    for (int i = tid; i < 507; i += 256) rel_lds[i] = rel[h * 507 + i];
    for (int i = tid; i < 14 * 32; i += 256) {
        int t = 98 + (i >> 5), d = i & 31;
        lh[VS + t * 40 + d] = (_Float16)0.f;
    }

    // ---------------- Stage 1: qkv slice GEMM via fp16 MFMA ----------------
    // A = x[b] (tokens x 128), B[k][n] = W[n][k]; N-tile nt: 0=Q,1=K,2=V rows.
    int tok = 32 * wv + t32; if (tok > 97) tok = 97;   // clamp: dup rows discarded
    const float* xrow = x + ((long)b * TOK + tok) * 128 + half * 8;

    f32x16 acc[3];
#pragma unroll
    for (int nt = 0; nt < 3; nt++)
#pragma unroll
        for (int i = 0; i < 16; i++) acc[nt][i] = 0.f;

#pragma unroll
    for (int kt = 0; kt < 8; ++kt) {
        float4 a0 = *(const float4*)(xrow + kt * 16);
        float4 a1 = *(const float4*)(xrow + kt * 16 + 4);
        half8 af = cvt8(a0, a1);
#pragma unroll
        for (int nt = 0; nt < 3; nt++) {
            const float* wr = qkv_w + ((long)(nt * 128 + h * 32 + t32)) * 128 + kt * 16 + half * 8;
            float4 b0 = *(const float4*)wr;
            float4 b1 = *(const float4*)(wr + 4);
            half8 bf = cvt8(b0, b1);
            acc[nt] = __builtin_amdgcn_mfma_f32_32x32x16_f16(af, bf, acc[nt], 0, 0, 0);
        }
    }

    // store Q (scaled+bias), K, V to LDS as fp16. C/D: col=lane&31, row=f(reg,half)
    {
        const float qb = qkv_b[h * 32 + t32];
        const float kb = qkv_b[128 + h * 32 + t32];
        const float vb = qkv_b[256 + h * 32 + t32];
#pragma unroll
        for (int reg = 0; reg < 16; ++reg) {
            int m = 32 * wv + (reg & 3) + 8 * (reg >> 2) + 4 * half;
            if (m < TOK) {
                lh[QS + m * 40 + t32] = (_Float16)((acc[0][reg] + qb) * QSCALE);
                lh[KS + m * 40 + t32] = (_Float16)(acc[1][reg] + kb);
                lh[VS + m * 40 + t32] = (_Float16)(acc[2][reg] + vb);
            }
        }
    }
    __syncthreads();

    // ---------------- Stage 2: S = Q K^T (rows [32wv,32wv+32), all 128 cols) ----
    f32x16 sacc[4];
#pragma unroll
    for (int nt = 0; nt < 4; nt++)
#pragma unroll
        for (int i = 0; i < 16; i++) sacc[nt][i] = 0.f;

#pragma unroll
    for (int kk = 0; kk < 2; ++kk) {
        half8 qa = *(const half8*)&lh[QS + (32 * wv + t32) * 40 + kk * 16 + half * 8];
#pragma unroll
        for (int nt = 0; nt < 4; ++nt) {
            half8 kf = *(const half8*)&lh[KS + (nt * 32 + t32) * 40 + kk * 16 + half * 8];
            sacc[nt] = __builtin_amdgcn_mfma_f32_32x32x16_f16(qa, kf, sacc[nt], 0, 0, 0);
        }
    }
    __syncthreads();   // all Qs/Ks reads done; Ps (overlapping) may now be written

    // ---------------- Stage 3: bias + mask + softmax ----------------
    const long mbase = (long)(b % Lmask) * (TOK * TOK);
    const int mrow0 = 32 * wv + 4 * half;

    int mterm[16];
#pragma unroll
    for (int reg = 0; reg < 16; ++reg) {
        int m = mrow0 + (reg & 3) + 8 * (reg >> 2);
        int mm = m > 97 ? 97 : m;
        int ti = mm / 49; int r2 = mm - 49 * ti; int hi = r2 / 7; int wi = r2 - 7 * hi;
        // offset 253 = 1*169 + 6*13 + 6 so that mterm - jterm == REL_IDX[m][j]
        mterm[reg] = ti * 169 + hi * 13 + wi + 253;
    }

#pragma unroll
    for (int nt = 0; nt < 4; ++nt) {
        int j = nt * 32 + t32;
        int tj = j / 49; int rj = j - 49 * tj; int hj = rj / 7; int wj = rj - 7 * hj;
        int jterm = tj * 169 + hj * 13 + wj;
        bool jv = (j < TOK);
        const float* mcol = mask + mbase + j;
#pragma unroll
        for (int reg = 0; reg < 16; ++reg) {
            int m = mrow0 + (reg & 3) + 8 * (reg >> 2);
            float s = -1e30f;
            if (jv && m < TOK)
                s = sacc[nt][reg] + rel_lds[mterm[reg] - jterm] + mcol[(long)m * TOK];
            sacc[nt][reg] = s;
        }
    }

    float rmax[16], rsum[16];
#pragma unroll
    for (int reg = 0; reg < 16; ++reg) {
        float v = fmaxf(fmaxf(sacc[0][reg], sacc[1][reg]), fmaxf(sacc[2][reg], sacc[3][reg]));
        v = fmaxf(v, __shfl_xor(v, 1));
        v = fmaxf(v, __shfl_xor(v, 2));
        v = fmaxf(v, __shfl_xor(v, 4));
        v = fmaxf(v, __shfl_xor(v, 8));
        v = fmaxf(v, __shfl_xor(v, 16));
        rmax[reg] = v;
        rsum[reg] = 0.f;
    }

#pragma unroll
    for (int nt = 0; nt < 4; ++nt) {
        int j = nt * 32 + t32;
#pragma unroll
        for (int reg = 0; reg < 16; ++reg) {
            int m = mrow0 + (reg & 3) + 8 * (reg >> 2);
            float p = __expf(sacc[nt][reg] - rmax[reg]);
            rsum[reg] += p;
            if (j < 112) lh[PS + m * 120 + j] = (_Float16)p;   // pad cols get exact 0
        }
    }

#pragma unroll
    for (int reg = 0; reg < 16; ++reg) {
        float v = rsum[reg];
        v += __shfl_xor(v, 1);
        v += __shfl_xor(v, 2);
        v += __shfl_xor(v, 4);
        v += __shfl_xor(v, 8);
        v += __shfl_xor(v, 16);
        rsum[reg] = 1.0f / v;
    }

    // ---------------- Stage 4: O = P V  (own P rows; V via strided u16 gather) ----
    f32x16 oacc;
#pragma unroll
    for (int i = 0; i < 16; i++) oacc[i] = 0.f;

#pragma unroll
    for (int kk = 0; kk < 7; ++kk) {
        half8 pa = *(const half8*)&lh[PS + (32 * wv + t32) * 120 + kk * 16 + half * 8];
        int tbase = kk * 16 + half * 8;
        half8 vf;
#pragma unroll
        for (int jj = 0; jj < 8; ++jj)
            vf[jj] = lh[VS + (tbase + jj) * 40 + t32];
        oacc = __builtin_amdgcn_mfma_f32_32x32x16_f16(pa, vf, oacc, 0, 0, 0);
    }

    float* ob = out + ((long)b * TOK) * 128 + h * 32 + t32;
#pragma unroll
    for (int reg = 0; reg < 16; ++reg) {
        int m = mrow0 + (reg & 3) + 8 * (reg >> 2);
        if (m < TOK) ob[(long)m * 128] = oacc[reg] * rsum[reg];
    }
}

// ---------------- Proj GEMM, in-place on d_out, fp16 MFMA ----------------
// Each wave owns 32 rows: reads them (A), reads proj_w (B), writes same 32 rows.
__global__ __launch_bounds__(256, 3) void proj_mfma(
    const float* __restrict__ proj_w,  // [128][128]
    const float* __restrict__ proj_b,  // [128]
    float* __restrict__ out,
    int totalRows)
{
    const int tid  = threadIdx.x;
    const int wv   = tid >> 6;
    const int lane = tid & 63;
    const int t32  = lane & 31;
    const int half = lane >> 5;

    const long rowb = (long)blockIdx.x * 128 + 32 * wv;
    long rr = rowb + t32; if (rr >= totalRows) rr = totalRows - 1;
    const float* arow = out + rr * 128 + half * 8;

    half8 af[8];
#pragma unroll
    for (int kt = 0; kt < 8; ++kt) {
        float4 a0 = *(const float4*)(arow + kt * 16);
        float4 a1 = *(const float4*)(arow + kt * 16 + 4);
        af[kt] = cvt8(a0, a1);
    }

    f32x16 acc[4];
#pragma unroll
    for (int nt = 0; nt < 4; nt++)
#pragma unroll
        for (int i = 0; i < 16; i++) acc[nt][i] = 0.f;

#pragma unroll
    for (int kt = 0; kt < 8; ++kt) {
#pragma unroll
        for (int nt = 0; nt < 4; ++nt) {
            const float* wr = proj_w + (long)(nt * 32 + t32) * 128 + kt * 16 + half * 8;
            float4 b0 = *(const float4*)wr;
            float4 b1 = *(const float4*)(wr + 4);
            half8 bf = cvt8(b0, b1);
            acc[nt] = __builtin_amdgcn_mfma_f32_32x32x16_f16(af[kt], bf, acc[nt], 0, 0, 0);
        }
    }

#pragma unroll
    for (int nt = 0; nt < 4; ++nt) {
        int co = nt * 32 + t32;
        float pb = proj_b[co];
#pragma unroll
        for (int reg = 0; reg < 16; ++reg) {
            long m = rowb + (reg & 3) + 8 * (reg >> 2) + 4 * half;
            if (m < totalRows) out[m * 128 + co] = acc[nt][reg] + pb;
        }
    }
}

extern "C" void kernel_launch(void* const* d_in, const int* in_sizes, int n_in,
                              void* d_out, int out_size, void* d_ws, size_t ws_size,
                              hipStream_t stream) {
    const float* x      = (const float*)d_in[0];
    const float* mask   = (const float*)d_in[1];
    const float* qkv_w  = (const float*)d_in[2];
    const float* qkv_b  = (const float*)d_in[3];
    const float* rel    = (const float*)d_in[4];
    const float* proj_w = (const float*)d_in[5];
    const float* proj_b = (const float*)d_in[6];
    float* out = (float*)d_out;

    const int B     = in_sizes[0] / (TOK * 128);
    const int Lmask = in_sizes[1] / (TOK * TOK);

    attn_mfma<<<B * 4, 256, 0, stream>>>(x, mask, qkv_w, qkv_b, rel, out, Lmask);

    const int totalRows = B * TOK;
    proj_mfma<<<(totalRows + 127) / 128, 256, 0, stream>>>(proj_w, proj_b, out, totalRows);
}